// Round 1
// baseline (377.607 us; speedup 1.0000x reference)
//
#include <hip/hip_runtime.h>
#include <math.h>

#define NEG_CONST (-9000000000000000.0f)
#define SCARE 11.313708498984761f  // sqrt(128)

// ---------------- kernel 1: out = A @ B (128x128 @ 128x128) ----------------
__global__ __launch_bounds__(256) void small_mm(const float* __restrict__ A,
                                                const float* __restrict__ B,
                                                float* __restrict__ out) {
    int r  = blockIdx.x * 8 + (threadIdx.x >> 5);
    int c0 = (threadIdx.x & 31) * 4;
    float a0 = 0.f, a1 = 0.f, a2 = 0.f, a3 = 0.f;
    for (int k = 0; k < 128; ++k) {
        float a = A[r * 128 + k];
        float4 b = *reinterpret_cast<const float4*>(&B[k * 128 + c0]);
        a0 += a * b.x; a1 += a * b.y; a2 += a * b.z; a3 += a * b.w;
    }
    float4 o = {a0, a1, a2, a3};
    *reinterpret_cast<float4*>(&out[r * 128 + c0]) = o;
}

// ------------- kernel 2: P = x @ W for 5 weight matrices (N=640) -------------
// grid: (ceil(n/64), 10). Each block: 64 rows x 64 cols, K=128 in chunks of 32.
__global__ __launch_bounds__(256) void proj_gemm(
    const float* __restrict__ x,
    const float* __restrict__ Q, const float* __restrict__ K,
    const float* __restrict__ Vm, const float* __restrict__ VK,
    const float* __restrict__ VV,
    float* __restrict__ xQ, float* __restrict__ xK, float* __restrict__ xV,
    float* __restrict__ xVK, float* __restrict__ xVV, int n)
{
    __shared__ __align__(16) float xs[32][68];  // [k][row] (transposed)
    __shared__ __align__(16) float ws[32][68];  // [k][col]

    const float* Wsel[5] = {Q, K, Vm, VK, VV};
    float*       Osel[5] = {xQ, xK, xV, xVK, xVV};
    int ct = blockIdx.y;               // 0..9
    const float* W = Wsel[ct >> 1];
    float*       O = Osel[ct >> 1];
    int half = (ct & 1) * 64;
    int row0 = blockIdx.x * 64;
    int tid = threadIdx.x;
    int tr = tid >> 4, tc = tid & 15;

    float acc[4][4] = {};
    for (int kk = 0; kk < 128; kk += 32) {
        for (int it = 0; it < 2; ++it) {
            int id = tid + it * 256;   // 0..511
            int r = id >> 3;           // 0..63
            int f = id & 7;            // float4 within k-chunk
            int grow = row0 + r;
            float4 v = (grow < n)
                ? *reinterpret_cast<const float4*>(&x[(size_t)grow * 128 + kk + f * 4])
                : make_float4(0.f, 0.f, 0.f, 0.f);
            xs[f * 4 + 0][r] = v.x; xs[f * 4 + 1][r] = v.y;
            xs[f * 4 + 2][r] = v.z; xs[f * 4 + 3][r] = v.w;
        }
        for (int it = 0; it < 2; ++it) {
            int id = tid + it * 256;   // 0..511
            int k = id >> 4;           // 0..31
            int c4 = id & 15;
            float4 v = *reinterpret_cast<const float4*>(&W[(size_t)(kk + k) * 128 + half + c4 * 4]);
            *reinterpret_cast<float4*>(&ws[k][c4 * 4]) = v;
        }
        __syncthreads();
        #pragma unroll
        for (int k = 0; k < 32; ++k) {
            float4 a = *reinterpret_cast<const float4*>(&xs[k][tr * 4]);
            float4 b = *reinterpret_cast<const float4*>(&ws[k][tc * 4]);
            float av[4] = {a.x, a.y, a.z, a.w};
            float bv[4] = {b.x, b.y, b.z, b.w};
            #pragma unroll
            for (int i2 = 0; i2 < 4; ++i2)
                #pragma unroll
                for (int j2 = 0; j2 < 4; ++j2)
                    acc[i2][j2] += av[i2] * bv[j2];
        }
        __syncthreads();
    }
    for (int i2 = 0; i2 < 4; ++i2) {
        int grow = row0 + tr * 4 + i2;
        if (grow < n) {
            float4 o = {acc[i2][0], acc[i2][1], acc[i2][2], acc[i2][3]};
            *reinterpret_cast<float4*>(&O[(size_t)grow * 128 + half + tc * 4]) = o;
        }
    }
}

// ---------------- kernel 3: per-node attention, 1 block = 1 node ----------------
__global__ __launch_bounds__(256) void node_attn(
    const int* __restrict__ nlist,
    const float* __restrict__ xQ, const float* __restrict__ xK,
    const float* __restrict__ xV, const float* __restrict__ xVK,
    const float* __restrict__ xVV,
    float* __restrict__ outp, int n)
{
    __shared__ int   nl_s[16];
    __shared__ float mk_s[16];
    __shared__ __align__(16) float Qn_s[16][132];
    __shared__ __align__(16) float Kn_s[16][132];
    __shared__ __align__(16) float xQi_s[128];
    __shared__ __align__(16) float xKi_s[128];
    __shared__ __align__(16) float xVi_s[128];
    __shared__ float a_s[16][17];
    __shared__ float t_s[16];
    __shared__ float a2_s[17];
    __shared__ float w_s[16];
    __shared__ float s200_s;
    __shared__ float red4_s[4];

    int i = blockIdx.x;
    int tid = threadIdx.x;

    if (tid < 16) {
        int v = nlist[(size_t)i * 16 + tid];
        nl_s[tid] = v;
        mk_s[tid] = (v != n - 1) ? 1.0f : 0.0f;
    }
    __syncthreads();

    // gather Qn = xQ[nl], Kn = xK[nl] into LDS (1024 float4s), plus center rows
    for (int id = tid; id < 1024; id += 256) {
        int which = id >> 9;
        int rem = id & 511;
        int r = rem >> 5;
        int f = rem & 31;
        const float* src = which ? xK : xQ;
        float4 v = *reinterpret_cast<const float4*>(&src[(size_t)nl_s[r] * 128 + f * 4]);
        float* dst = which ? &Kn_s[r][f * 4] : &Qn_s[r][f * 4];
        *reinterpret_cast<float4*>(dst) = v;
    }
    if (tid < 96) {
        int which = tid >> 5; int f = tid & 31;
        const float* src = (which == 0) ? xQ : ((which == 1) ? xK : xV);
        float* dst = (which == 0) ? xQi_s : ((which == 1) ? xKi_s : xVi_s);
        float4 v = *reinterpret_cast<const float4*>(&src[(size_t)i * 128 + f * 4]);
        *reinterpret_cast<float4*>(&dst[f * 4]) = v;
    }
    __syncthreads();

    // stage-1 scores: s[r][c] = Qn[r]·Kn[c]; leaky -> mask -> *scare -> row softmax
    {
        int r = tid >> 4, c = tid & 15;
        float acc = 0.f;
        #pragma unroll
        for (int f = 0; f < 32; ++f) {
            float4 a = *reinterpret_cast<const float4*>(&Qn_s[r][f * 4]);
            float4 b = *reinterpret_cast<const float4*>(&Kn_s[c][f * 4]);
            acc += a.x * b.x + a.y * b.y + a.z * b.z + a.w * b.w;
        }
        float slr = acc > 0.f ? acc : 0.01f * acc;
        float sm = (mk_s[r] * mk_s[c] > 0.f) ? slr : NEG_CONST;
        sm *= SCARE;
        float m = sm;
        for (int off = 8; off >= 1; off >>= 1)
            m = fmaxf(m, __shfl_xor(m, off, 64));
        float p = expf(sm - m);
        float ssum = p;
        for (int off = 8; off >= 1; off >>= 1)
            ssum += __shfl_xor(ssum, off, 64);
        a_s[r][c] = p / ssum;
    }
    __syncthreads();

    // t[g] = xVK[nl[g]] · xQ[i]  (16 groups x 16 lanes, 8 elems each)
    {
        int g = tid >> 4, sub = tid & 15;
        const float* row = &xVK[(size_t)nl_s[g] * 128 + sub * 8];
        float4 v0 = *reinterpret_cast<const float4*>(row);
        float4 v1 = *reinterpret_cast<const float4*>(row + 4);
        const float* q = &xQi_s[sub * 8];
        float part = v0.x * q[0] + v0.y * q[1] + v0.z * q[2] + v0.w * q[3]
                   + v1.x * q[4] + v1.y * q[5] + v1.z * q[6] + v1.w * q[7];
        for (int off = 8; off >= 1; off >>= 1)
            part += __shfl_xor(part, off, 64);
        if (sub == 0) t_s[g] = part;
    }
    if (tid < 16) {
        const float* q = &xQi_s[tid * 8];
        const float* kk = &xKi_s[tid * 8];
        float part = 0.f;
        #pragma unroll
        for (int u = 0; u < 8; ++u) part += q[u] * kk[u];
        for (int off = 8; off >= 1; off >>= 1)
            part += __shfl_xor(part, off, 64);
        if (tid == 0) s200_s = part;
    }
    __syncthreads();

    // stage-2 scores (17) + softmax, on lanes 0..31 of wave 0
    if (tid < 32) {
        int j = tid;
        float val;
        if (j == 0) {
            float v = s200_s * SCARE;
            val = v > 0.f ? v : 0.01f * v;
        } else if (j <= 16) {
            int k = j - 1;
            float dot = 0.f;
            #pragma unroll
            for (int u = 0; u < 16; ++u) dot += a_s[k][u] * t_s[u];
            float v = dot * SCARE;
            v = v > 0.f ? v : 0.01f * v;
            val = (mk_s[k] > 0.f) ? v : NEG_CONST;
        } else {
            val = -3.0e38f;
        }
        float m = val;
        for (int off = 16; off >= 1; off >>= 1)
            m = fmaxf(m, __shfl_xor(m, off, 64));
        float p = (j <= 16) ? expf(val - m) : 0.f;
        float ssum = p;
        for (int off = 16; off >= 1; off >>= 1)
            ssum += __shfl_xor(ssum, off, 64);
        if (j <= 16) a2_s[j] = p / ssum;
    }
    __syncthreads();

    // w[k] = sum_j a2[j+1] * a[j][k]
    if (tid < 16) {
        float acc = 0.f;
        #pragma unroll
        for (int j2 = 0; j2 < 16; ++j2) acc += a2_s[j2 + 1] * a_s[j2][tid];
        w_s[tid] = acc;
    }
    __syncthreads();

    // out_h = a2[0]*xV[i][h] + sum_k w[k]*xVV[nl[k]][h];  then L2-normalize
    float outv = 0.f;
    if (tid < 128) {
        outv = a2_s[0] * xVi_s[tid];
        #pragma unroll
        for (int k = 0; k < 16; ++k)
            outv += w_s[k] * xVV[(size_t)nl_s[k] * 128 + tid];
    }
    float sq = outv * outv;
    for (int off = 32; off >= 1; off >>= 1)
        sq += __shfl_xor(sq, off, 64);
    if ((tid & 63) == 0) red4_s[tid >> 6] = sq;
    __syncthreads();
    if (tid < 128) {
        float nrm = sqrtf(red4_s[0] + red4_s[1] + red4_s[2] + red4_s[3]);
        float denom = fmaxf(nrm, 1e-12f);
        outp[(size_t)i * 128 + tid] = outv / denom;
    }
}

extern "C" void kernel_launch(void* const* d_in, const int* in_sizes, int n_in,
                              void* d_out, int out_size, void* d_ws, size_t ws_size,
                              hipStream_t stream) {
    const float* x     = (const float*)d_in[0];
    const int*   nlist = (const int*)d_in[1];
    const float* Q     = (const float*)d_in[2];
    const float* K     = (const float*)d_in[3];
    const float* V     = (const float*)d_in[4];
    float* out = (float*)d_out;
    int n = in_sizes[0] / 128;                 // 50000

    float* ws  = (float*)d_ws;
    float* VK  = ws;                           // 16384 floats
    float* VV  = ws + 16384;                   // 16384 floats
    float* xQ  = ws + 32768;
    size_t stride = (size_t)n * 128;
    float* xK  = xQ  + stride;
    float* xV  = xK  + stride;
    float* xVK = xV  + stride;
    float* xVV = xVK + stride;

    small_mm<<<dim3(16), 256, 0, stream>>>(V, K, VK);
    small_mm<<<dim3(16), 256, 0, stream>>>(V, V, VV);
    dim3 g2((n + 63) / 64, 10);
    proj_gemm<<<g2, 256, 0, stream>>>(x, Q, K, V, VK, VV, xQ, xK, xV, xVK, xVV, n);
    node_attn<<<n, 256, 0, stream>>>(nlist, xQ, xK, xV, xVK, xVV, out, n);
}

// Round 2
// 370.335 us; speedup vs baseline: 1.0196x; 1.0196x over previous
//
#include <hip/hip_runtime.h>
#include <math.h>

#define NEG_CONST (-9000000000000000.0f)
#define SCARE 11.313708498984761f  // sqrt(128)

// -------- kernel 1: VK = V@K, VV = V@V (two 128x128 GEMMs, grid (16,2)) --------
__global__ __launch_bounds__(256) void small_mm2(const float* __restrict__ V,
                                                 const float* __restrict__ K,
                                                 float* __restrict__ VK,
                                                 float* __restrict__ VV) {
    const float* B = blockIdx.y ? V : K;
    float* out = blockIdx.y ? VV : VK;
    int r  = blockIdx.x * 8 + (threadIdx.x >> 5);
    int c0 = (threadIdx.x & 31) * 4;
    float a0 = 0.f, a1 = 0.f, a2 = 0.f, a3 = 0.f;
    for (int k = 0; k < 128; ++k) {
        float a = V[r * 128 + k];
        float4 b = *reinterpret_cast<const float4*>(&B[k * 128 + c0]);
        a0 += a * b.x; a1 += a * b.y; a2 += a * b.z; a3 += a * b.w;
    }
    float4 o = {a0, a1, a2, a3};
    *reinterpret_cast<float4*>(&out[r * 128 + c0]) = o;
}

// ------- kernel 2: P = x @ W for 5 weights; 128x128 tile, 8x8 per thread -------
__global__ __launch_bounds__(256) void proj_gemm(
    const float* __restrict__ x,
    const float* __restrict__ Q, const float* __restrict__ K,
    const float* __restrict__ Vm, const float* __restrict__ VK,
    const float* __restrict__ VV,
    float* __restrict__ xQ, float* __restrict__ xK, float* __restrict__ xV,
    float* __restrict__ xVK, float* __restrict__ xVV, int n)
{
    __shared__ __align__(16) float xs[32][132];  // [k][row] (transposed)
    __shared__ __align__(16) float ws[32][132];  // [k][col]

    const float* Wsel[5] = {Q, K, Vm, VK, VV};
    float*       Osel[5] = {xQ, xK, xV, xVK, xVV};
    const float* W = Wsel[blockIdx.y];
    float*       O = Osel[blockIdx.y];
    int row0 = blockIdx.x * 128;
    int tid = threadIdx.x;
    int tr = tid >> 4, tc = tid & 15;

    float acc[8][8] = {};
    for (int kk = 0; kk < 128; kk += 32) {
        #pragma unroll
        for (int it = 0; it < 4; ++it) {
            int id = tid + it * 256;   // 0..1023
            int r = id >> 3;           // 0..127
            int f = id & 7;            // float4 within k-chunk
            int grow = row0 + r;
            float4 v = (grow < n)
                ? *reinterpret_cast<const float4*>(&x[(size_t)grow * 128 + kk + f * 4])
                : make_float4(0.f, 0.f, 0.f, 0.f);
            xs[f * 4 + 0][r] = v.x; xs[f * 4 + 1][r] = v.y;
            xs[f * 4 + 2][r] = v.z; xs[f * 4 + 3][r] = v.w;
        }
        #pragma unroll
        for (int it = 0; it < 4; ++it) {
            int id = tid + it * 256;   // 0..1023
            int k = id >> 5;           // 0..31
            int c4 = id & 31;
            *reinterpret_cast<float4*>(&ws[k][c4 * 4]) =
                *reinterpret_cast<const float4*>(&W[(size_t)(kk + k) * 128 + c4 * 4]);
        }
        __syncthreads();
        #pragma unroll 4
        for (int k = 0; k < 32; ++k) {
            float4 a0 = *reinterpret_cast<const float4*>(&xs[k][tr * 8]);
            float4 a1 = *reinterpret_cast<const float4*>(&xs[k][tr * 8 + 4]);
            float4 b0 = *reinterpret_cast<const float4*>(&ws[k][tc * 8]);
            float4 b1 = *reinterpret_cast<const float4*>(&ws[k][tc * 8 + 4]);
            float av[8] = {a0.x, a0.y, a0.z, a0.w, a1.x, a1.y, a1.z, a1.w};
            float bv[8] = {b0.x, b0.y, b0.z, b0.w, b1.x, b1.y, b1.z, b1.w};
            #pragma unroll
            for (int i2 = 0; i2 < 8; ++i2)
                #pragma unroll
                for (int j2 = 0; j2 < 8; ++j2)
                    acc[i2][j2] += av[i2] * bv[j2];
        }
        __syncthreads();
    }
    #pragma unroll
    for (int i2 = 0; i2 < 8; ++i2) {
        int grow = row0 + tr * 8 + i2;
        if (grow < n) {
            float4 o0 = {acc[i2][0], acc[i2][1], acc[i2][2], acc[i2][3]};
            float4 o1 = {acc[i2][4], acc[i2][5], acc[i2][6], acc[i2][7]};
            *reinterpret_cast<float4*>(&O[(size_t)grow * 128 + tc * 8])     = o0;
            *reinterpret_cast<float4*>(&O[(size_t)grow * 128 + tc * 8 + 4]) = o1;
        }
    }
}

// ---------------- kernel 3: per-node attention, 1 block = 1 node ----------------
__global__ __launch_bounds__(256) void node_attn(
    const int* __restrict__ nlist,
    const float* __restrict__ xQ, const float* __restrict__ xK,
    const float* __restrict__ xV, const float* __restrict__ xVK,
    const float* __restrict__ xVV,
    float* __restrict__ outp, int n)
{
    __shared__ int   nl_s[16];
    __shared__ float mk_s[16];
    __shared__ __align__(16) float Qn_s[16][132];
    __shared__ __align__(16) float Kn_s[16][132];
    __shared__ __align__(16) float xQi_s[128];
    __shared__ __align__(16) float xKi_s[128];
    __shared__ __align__(16) float xVi_s[128];
    __shared__ __align__(16) float4 ps4[4][64];   // stage-1 partials [q][tile]
    __shared__ float a_s[16][17];
    __shared__ float t_s[16];
    __shared__ float a2_s[17];
    __shared__ float w_s[16];
    __shared__ float s200_s;
    __shared__ float red4_s[4];

    int i = blockIdx.x;
    int tid = threadIdx.x;

    if (tid < 16) {
        int v = nlist[(size_t)i * 16 + tid];
        nl_s[tid] = v;
        mk_s[tid] = (v != n - 1) ? 1.0f : 0.0f;
    }
    __syncthreads();

    // gather Qn = xQ[nl], Kn = xK[nl] into LDS (1024 float4s), plus center rows
    for (int id = tid; id < 1024; id += 256) {
        int which = id >> 9;
        int rem = id & 511;
        int r = rem >> 5;
        int f = rem & 31;
        const float* src = which ? xK : xQ;
        float4 v = *reinterpret_cast<const float4*>(&src[(size_t)nl_s[r] * 128 + f * 4]);
        float* dst = which ? &Kn_s[r][f * 4] : &Qn_s[r][f * 4];
        *reinterpret_cast<float4*>(dst) = v;
    }
    if (tid < 96) {
        int which = tid >> 5; int f = tid & 31;
        const float* src = (which == 0) ? xQ : ((which == 1) ? xK : xV);
        float* dst = (which == 0) ? xQi_s : ((which == 1) ? xKi_s : xVi_s);
        float4 v = *reinterpret_cast<const float4*>(&src[(size_t)i * 128 + f * 4]);
        *reinterpret_cast<float4*>(&dst[f * 4]) = v;
    }
    __syncthreads();

    // stage-1 scores: 2x2 register tile per thread, K split across 4 waves
    {
        int q = tid >> 6;              // wave id = K-chunk index
        int tile = tid & 63;
        int tr2 = (tile >> 3) * 2;     // row pair
        int tc2 = (tile & 7) * 2;      // col pair
        int base = q * 32;
        float a00 = 0.f, a01 = 0.f, a10 = 0.f, a11 = 0.f;
        #pragma unroll
        for (int f = 0; f < 8; ++f) {
            float4 qa = *reinterpret_cast<const float4*>(&Qn_s[tr2 + 0][base + f * 4]);
            float4 qb = *reinterpret_cast<const float4*>(&Qn_s[tr2 + 1][base + f * 4]);
            float4 ka = *reinterpret_cast<const float4*>(&Kn_s[tc2 + 0][base + f * 4]);
            float4 kb = *reinterpret_cast<const float4*>(&Kn_s[tc2 + 1][base + f * 4]);
            a00 += qa.x * ka.x + qa.y * ka.y + qa.z * ka.z + qa.w * ka.w;
            a01 += qa.x * kb.x + qa.y * kb.y + qa.z * kb.z + qa.w * kb.w;
            a10 += qb.x * ka.x + qb.y * ka.y + qb.z * ka.z + qb.w * ka.w;
            a11 += qb.x * kb.x + qb.y * kb.y + qb.z * kb.z + qb.w * kb.w;
        }
        ps4[q][tile] = make_float4(a00, a01, a10, a11);
    }
    __syncthreads();

    // combine partials; leaky -> mask -> *scare -> row softmax
    {
        int r = tid >> 4, c = tid & 15;
        const float* p = reinterpret_cast<const float*>(ps4);
        int off = ((r >> 1) * 8 + (c >> 1)) * 4 + (r & 1) * 2 + (c & 1);
        float acc = p[off] + p[off + 256] + p[off + 512] + p[off + 768];
        float slr = acc > 0.f ? acc : 0.01f * acc;
        float sm = (mk_s[r] * mk_s[c] > 0.f) ? slr : NEG_CONST;
        sm *= SCARE;
        float m = sm;
        for (int off2 = 8; off2 >= 1; off2 >>= 1)
            m = fmaxf(m, __shfl_xor(m, off2, 64));
        float pp = expf(sm - m);
        float ssum = pp;
        for (int off2 = 8; off2 >= 1; off2 >>= 1)
            ssum += __shfl_xor(ssum, off2, 64);
        a_s[r][c] = pp / ssum;
    }
    __syncthreads();

    // t[g] = xVK[nl[g]] . xQ[i]  (16 groups x 16 lanes, 8 elems each)
    {
        int g = tid >> 4, sub = tid & 15;
        const float* row = &xVK[(size_t)nl_s[g] * 128 + sub * 8];
        float4 v0 = *reinterpret_cast<const float4*>(row);
        float4 v1 = *reinterpret_cast<const float4*>(row + 4);
        const float* q = &xQi_s[sub * 8];
        float part = v0.x * q[0] + v0.y * q[1] + v0.z * q[2] + v0.w * q[3]
                   + v1.x * q[4] + v1.y * q[5] + v1.z * q[6] + v1.w * q[7];
        for (int off = 8; off >= 1; off >>= 1)
            part += __shfl_xor(part, off, 64);
        if (sub == 0) t_s[g] = part;
    }
    if (tid < 16) {
        const float* q = &xQi_s[tid * 8];
        const float* kk = &xKi_s[tid * 8];
        float part = 0.f;
        #pragma unroll
        for (int u = 0; u < 8; ++u) part += q[u] * kk[u];
        for (int off = 8; off >= 1; off >>= 1)
            part += __shfl_xor(part, off, 64);
        if (tid == 0) s200_s = part;
    }
    __syncthreads();

    // stage-2 scores (17) + softmax, on lanes 0..31 of wave 0
    if (tid < 32) {
        int j = tid;
        float val;
        if (j == 0) {
            float v = s200_s * SCARE;
            val = v > 0.f ? v : 0.01f * v;
        } else if (j <= 16) {
            int k = j - 1;
            float dot = 0.f;
            #pragma unroll
            for (int u = 0; u < 16; ++u) dot += a_s[k][u] * t_s[u];
            float v = dot * SCARE;
            v = v > 0.f ? v : 0.01f * v;
            val = (mk_s[k] > 0.f) ? v : NEG_CONST;
        } else {
            val = -3.0e38f;
        }
        float m = val;
        for (int off = 16; off >= 1; off >>= 1)
            m = fmaxf(m, __shfl_xor(m, off, 64));
        float p = (j <= 16) ? expf(val - m) : 0.f;
        float ssum = p;
        for (int off = 16; off >= 1; off >>= 1)
            ssum += __shfl_xor(ssum, off, 64);
        if (j <= 16) a2_s[j] = p / ssum;
    }
    __syncthreads();

    // w[k] = sum_j a2[j+1] * a[j][k]
    if (tid < 16) {
        float acc = 0.f;
        #pragma unroll
        for (int j2 = 0; j2 < 16; ++j2) acc += a2_s[j2 + 1] * a_s[j2][tid];
        w_s[tid] = acc;
    }
    __syncthreads();

    // out_h = a2[0]*xV[i][h] + sum_k w[k]*xVV[nl[k]][h];  then L2-normalize
    float outv = 0.f;
    if (tid < 128) {
        outv = a2_s[0] * xVi_s[tid];
        #pragma unroll
        for (int k = 0; k < 16; ++k)
            outv += w_s[k] * xVV[(size_t)nl_s[k] * 128 + tid];
    }
    float sq = outv * outv;
    for (int off = 32; off >= 1; off >>= 1)
        sq += __shfl_xor(sq, off, 64);
    if ((tid & 63) == 0) red4_s[tid >> 6] = sq;
    __syncthreads();
    if (tid < 128) {
        float nrm = sqrtf(red4_s[0] + red4_s[1] + red4_s[2] + red4_s[3]);
        float denom = fmaxf(nrm, 1e-12f);
        outp[(size_t)i * 128 + tid] = outv / denom;
    }
}

extern "C" void kernel_launch(void* const* d_in, const int* in_sizes, int n_in,
                              void* d_out, int out_size, void* d_ws, size_t ws_size,
                              hipStream_t stream) {
    const float* x     = (const float*)d_in[0];
    const int*   nlist = (const int*)d_in[1];
    const float* Q     = (const float*)d_in[2];
    const float* K     = (const float*)d_in[3];
    const float* V     = (const float*)d_in[4];
    float* out = (float*)d_out;
    int n = in_sizes[0] / 128;                 // 50000

    float* ws  = (float*)d_ws;
    float* VK  = ws;                           // 16384 floats
    float* VV  = ws + 16384;                   // 16384 floats
    float* xQ  = ws + 32768;
    size_t stride = (size_t)n * 128;
    float* xK  = xQ  + stride;
    float* xV  = xK  + stride;
    float* xVK = xV  + stride;
    float* xVV = xVK + stride;

    small_mm2<<<dim3(16, 2), 256, 0, stream>>>(V, K, VK, VV);
    dim3 g2((n + 127) / 128, 5);
    proj_gemm<<<g2, 256, 0, stream>>>(x, Q, K, V, VK, VV, xQ, xK, xV, xVK, xVV, n);
    node_attn<<<n, 256, 0, stream>>>(nlist, xQ, xK, xV, xVK, xVV, out, n);
}

// Round 3
// 316.011 us; speedup vs baseline: 1.1949x; 1.1719x over previous
//
#include <hip/hip_runtime.h>
#include <math.h>

#define NEG_CONST (-9000000000000000.0f)
#define SCARE 11.313708498984761f  // sqrt(128)

__device__ __forceinline__ void wave_lds_fence() {
    __builtin_amdgcn_wave_barrier();
    asm volatile("s_waitcnt lgkmcnt(0)" ::: "memory");
    __builtin_amdgcn_wave_barrier();
}

// ---- kernel 1: y=0: QKt = Q @ K^T ; y=1: VV = V @ V  (grid (16,2)) ----
__global__ __launch_bounds__(256) void small_mm_a(const float* __restrict__ Q,
                                                  const float* __restrict__ K,
                                                  const float* __restrict__ V,
                                                  float* __restrict__ QKt,
                                                  float* __restrict__ VV) {
    int r  = blockIdx.x * 8 + (threadIdx.x >> 5);
    int c0 = (threadIdx.x & 31) * 4;
    float a0 = 0.f, a1 = 0.f, a2 = 0.f, a3 = 0.f;
    if (blockIdx.y == 0) {
        for (int k = 0; k < 128; k += 4) {
            float4 q  = *reinterpret_cast<const float4*>(&Q[r * 128 + k]);
            float4 k0 = *reinterpret_cast<const float4*>(&K[(c0 + 0) * 128 + k]);
            float4 k1 = *reinterpret_cast<const float4*>(&K[(c0 + 1) * 128 + k]);
            float4 k2 = *reinterpret_cast<const float4*>(&K[(c0 + 2) * 128 + k]);
            float4 k3 = *reinterpret_cast<const float4*>(&K[(c0 + 3) * 128 + k]);
            a0 += q.x*k0.x + q.y*k0.y + q.z*k0.z + q.w*k0.w;
            a1 += q.x*k1.x + q.y*k1.y + q.z*k1.z + q.w*k1.w;
            a2 += q.x*k2.x + q.y*k2.y + q.z*k2.z + q.w*k2.w;
            a3 += q.x*k3.x + q.y*k3.y + q.z*k3.z + q.w*k3.w;
        }
        float4 o = {a0, a1, a2, a3};
        *reinterpret_cast<float4*>(&QKt[r * 128 + c0]) = o;
    } else {
        for (int k = 0; k < 128; ++k) {
            float a = V[r * 128 + k];
            float4 b = *reinterpret_cast<const float4*>(&V[k * 128 + c0]);
            a0 += a * b.x; a1 += a * b.y; a2 += a * b.z; a3 += a * b.w;
        }
        float4 o = {a0, a1, a2, a3};
        *reinterpret_cast<float4*>(&VV[r * 128 + c0]) = o;
    }
}

// ---- kernel 2: MT = QKt @ V^T  (grid 16) ----
__global__ __launch_bounds__(256) void small_mm_b(const float* __restrict__ QKt,
                                                  const float* __restrict__ V,
                                                  float* __restrict__ MT) {
    int r  = blockIdx.x * 8 + (threadIdx.x >> 5);
    int c0 = (threadIdx.x & 31) * 4;
    float a0 = 0.f, a1 = 0.f, a2 = 0.f, a3 = 0.f;
    for (int k = 0; k < 128; k += 4) {
        float4 q  = *reinterpret_cast<const float4*>(&QKt[r * 128 + k]);
        float4 k0 = *reinterpret_cast<const float4*>(&V[(c0 + 0) * 128 + k]);
        float4 k1 = *reinterpret_cast<const float4*>(&V[(c0 + 1) * 128 + k]);
        float4 k2 = *reinterpret_cast<const float4*>(&V[(c0 + 2) * 128 + k]);
        float4 k3 = *reinterpret_cast<const float4*>(&V[(c0 + 3) * 128 + k]);
        a0 += q.x*k0.x + q.y*k0.y + q.z*k0.z + q.w*k0.w;
        a1 += q.x*k1.x + q.y*k1.y + q.z*k1.z + q.w*k1.w;
        a2 += q.x*k2.x + q.y*k2.y + q.z*k2.z + q.w*k2.w;
        a3 += q.x*k3.x + q.y*k3.y + q.z*k3.z + q.w*k3.w;
    }
    float4 o = {a0, a1, a2, a3};
    *reinterpret_cast<float4*>(&MT[r * 128 + c0]) = o;
}

// ---- kernel 3: P = x @ W for 4 weights; 128x128 tile, 8x8 per thread ----
__global__ __launch_bounds__(256) void proj_gemm(
    const float* __restrict__ x,
    const float* __restrict__ W0, const float* __restrict__ W1,
    const float* __restrict__ W2, const float* __restrict__ W3,
    float* __restrict__ O0, float* __restrict__ O1,
    float* __restrict__ O2, float* __restrict__ O3, int n)
{
    __shared__ __align__(16) float xs[32][132];  // [k][row] (transposed)
    __shared__ __align__(16) float ws[32][132];  // [k][col]

    const float* Wsel[4] = {W0, W1, W2, W3};
    float*       Osel[4] = {O0, O1, O2, O3};
    const float* W = Wsel[blockIdx.y];
    float*       O = Osel[blockIdx.y];
    int row0 = blockIdx.x * 128;
    int tid = threadIdx.x;
    int tr = tid >> 4, tc = tid & 15;

    float acc[8][8] = {};
    for (int kk = 0; kk < 128; kk += 32) {
        #pragma unroll
        for (int it = 0; it < 4; ++it) {
            int id = tid + it * 256;
            int r = id >> 3;
            int f = id & 7;
            int grow = row0 + r;
            float4 v = (grow < n)
                ? *reinterpret_cast<const float4*>(&x[(size_t)grow * 128 + kk + f * 4])
                : make_float4(0.f, 0.f, 0.f, 0.f);
            xs[f * 4 + 0][r] = v.x; xs[f * 4 + 1][r] = v.y;
            xs[f * 4 + 2][r] = v.z; xs[f * 4 + 3][r] = v.w;
        }
        #pragma unroll
        for (int it = 0; it < 4; ++it) {
            int id = tid + it * 256;
            int k = id >> 5;
            int c4 = id & 31;
            *reinterpret_cast<float4*>(&ws[k][c4 * 4]) =
                *reinterpret_cast<const float4*>(&W[(size_t)(kk + k) * 128 + c4 * 4]);
        }
        __syncthreads();
        #pragma unroll 4
        for (int k = 0; k < 32; ++k) {
            float4 a0 = *reinterpret_cast<const float4*>(&xs[k][tr * 8]);
            float4 a1 = *reinterpret_cast<const float4*>(&xs[k][tr * 8 + 4]);
            float4 b0 = *reinterpret_cast<const float4*>(&ws[k][tc * 8]);
            float4 b1 = *reinterpret_cast<const float4*>(&ws[k][tc * 8 + 4]);
            float av[8] = {a0.x, a0.y, a0.z, a0.w, a1.x, a1.y, a1.z, a1.w};
            float bv[8] = {b0.x, b0.y, b0.z, b0.w, b1.x, b1.y, b1.z, b1.w};
            #pragma unroll
            for (int i2 = 0; i2 < 8; ++i2)
                #pragma unroll
                for (int j2 = 0; j2 < 8; ++j2)
                    acc[i2][j2] += av[i2] * bv[j2];
        }
        __syncthreads();
    }
    #pragma unroll
    for (int i2 = 0; i2 < 8; ++i2) {
        int grow = row0 + tr * 8 + i2;
        if (grow < n) {
            float4 o0 = {acc[i2][0], acc[i2][1], acc[i2][2], acc[i2][3]};
            float4 o1 = {acc[i2][4], acc[i2][5], acc[i2][6], acc[i2][7]};
            *reinterpret_cast<float4*>(&O[(size_t)grow * 128 + tc * 8])     = o0;
            *reinterpret_cast<float4*>(&O[(size_t)grow * 128 + tc * 8 + 4]) = o1;
        }
    }
}

// ---- kernel 4: per-node attention, 1 WAVE = 1 node, 4 nodes/block, no barriers ----
__global__ __launch_bounds__(256) void node_attn(
    const int* __restrict__ nlist,
    const float* __restrict__ x,
    const float* __restrict__ xQK,
    const float* __restrict__ u,
    const float* __restrict__ xV,
    const float* __restrict__ xVV,
    float* __restrict__ outp, int n)
{
    __shared__ __align__(16) float Bs[4][16][132];  // per-wave x[nl] rows

    int tid = threadIdx.x;
    int wid = tid >> 6;
    int l   = tid & 63;
    int g   = l >> 2;   // row/group 0..15
    int jj  = l & 3;    // 32-float chunk within row
    int i = blockIdx.x * 4 + wid;
    if (i >= n) return;

    int nlv = 0;
    if (l < 16) nlv = nlist[(size_t)i * 16 + l];
    unsigned long long mb = __ballot(l < 16 ? (nlv != n - 1) : 0);
    int nl_g = __shfl(nlv, g, 64);

    // A = xQK[nl_g] chunk jj (rotated order), B = x[nl] -> LDS (same rotation)
    float4 A[8];
    size_t rowbase = (size_t)nl_g * 128 + jj * 32;
    #pragma unroll
    for (int k4 = 0; k4 < 8; ++k4) {
        int rc = ((k4 + jj * 2) & 7) * 4;
        A[k4] = *reinterpret_cast<const float4*>(&xQK[rowbase + rc]);
    }
    #pragma unroll
    for (int k4 = 0; k4 < 8; ++k4) {
        int rc = ((k4 + jj * 2) & 7) * 4;
        float4 v = *reinterpret_cast<const float4*>(&x[rowbase + rc]);
        *reinterpret_cast<float4*>(&Bs[wid][g][jj * 32 + rc]) = v;
    }

    // s200 = xQK[i] . x[i] while the gather is in flight
    float2 qa = *reinterpret_cast<const float2*>(&xQK[(size_t)i * 128 + l * 2]);
    float2 xa = *reinterpret_cast<const float2*>(&x[(size_t)i * 128 + l * 2]);
    float s200 = qa.x * xa.x + qa.y * xa.y;
    #pragma unroll
    for (int off = 32; off >= 1; off >>= 1)
        s200 += __shfl_xor(s200, off, 64);

    wave_lds_fence();

    // stage-1: sc[c] = xQK[nl_g] . x[nl_c] (partial over chunk jj, reduce over 4 lanes)
    float a[16];
    {
        float sc[16];
        #pragma unroll
        for (int c = 0; c < 16; ++c) {
            float acc = 0.f;
            #pragma unroll
            for (int k4 = 0; k4 < 8; ++k4) {
                int rc = ((k4 + jj * 2) & 7) * 4;
                float4 b = *reinterpret_cast<const float4*>(&Bs[wid][c][jj * 32 + rc]);
                acc += A[k4].x * b.x + A[k4].y * b.y + A[k4].z * b.z + A[k4].w * b.w;
            }
            acc += __shfl_xor(acc, 1, 64);
            acc += __shfl_xor(acc, 2, 64);
            sc[c] = acc;
        }
        bool rlive = (mb >> g) & 1ULL;
        float m = -3.0e38f;
        #pragma unroll
        for (int c = 0; c < 16; ++c) {
            float s = sc[c];
            float slr = s > 0.f ? s : 0.01f * s;
            bool live = rlive && ((mb >> c) & 1ULL);
            float sm = (live ? slr : NEG_CONST) * SCARE;
            sc[c] = sm;
            m = fmaxf(m, sm);
        }
        float ssum = 0.f;
        #pragma unroll
        for (int c = 0; c < 16; ++c) { float p = __expf(sc[c] - m); a[c] = p; ssum += p; }
        float rs = 1.f / ssum;
        #pragma unroll
        for (int c = 0; c < 16; ++c) a[c] *= rs;
    }

    // t_g = u[i] . x[nl_g]
    float tmine;
    {
        float acc = 0.f;
        #pragma unroll
        for (int k4 = 0; k4 < 8; ++k4) {
            int rc = ((k4 + jj * 2) & 7) * 4;
            float4 uu = *reinterpret_cast<const float4*>(&u[(size_t)i * 128 + jj * 32 + rc]);
            float4 b  = *reinterpret_cast<const float4*>(&Bs[wid][g][jj * 32 + rc]);
            acc += uu.x * b.x + uu.y * b.y + uu.z * b.z + uu.w * b.w;
        }
        acc += __shfl_xor(acc, 1, 64);
        acc += __shfl_xor(acc, 2, 64);
        tmine = acc;
    }
    float t[16];
    #pragma unroll
    for (int k = 0; k < 16; ++k) t[k] = __shfl(tmine, k * 4, 64);

    // stage-2 logit for this group (j = g+1): scare -> leaky -> mask
    float lg = 0.f;
    #pragma unroll
    for (int k = 0; k < 16; ++k) lg += a[k] * t[k];
    {
        float v = lg * SCARE;
        v = v > 0.f ? v : 0.01f * v;
        lg = ((mb >> g) & 1ULL) ? v : NEG_CONST;
    }
    float v0 = s200 * SCARE;
    v0 = v0 > 0.f ? v0 : 0.01f * v0;

    float m17 = lg;
    #pragma unroll
    for (int off = 4; off <= 32; off <<= 1)
        m17 = fmaxf(m17, __shfl_xor(m17, off, 64));
    m17 = fmaxf(m17, v0);
    float pg = __expf(lg - m17);
    float sg = pg;
    #pragma unroll
    for (int off = 4; off <= 32; off <<= 1)
        sg += __shfl_xor(sg, off, 64);
    float p0 = __expf(v0 - m17);
    float inv = 1.f / (sg + p0);
    float a2g = pg * inv;   // a2[g+1] (replicated within group)
    float a20 = p0 * inv;

    // w[k] = sum_g a2[g+1] * a[g][k]  (cross-group shfl reduce)
    float w[16];
    #pragma unroll
    for (int k = 0; k < 16; ++k) {
        float wv = a2g * a[k];
        #pragma unroll
        for (int off = 4; off <= 32; off <<= 1)
            wv += __shfl_xor(wv, off, 64);
        w[k] = wv;
    }

    // out pair (h = 2l, 2l+1): a2_0 * xV[i] + sum_k w[k] * xVV[nl_k]
    float2 xv = *reinterpret_cast<const float2*>(&xV[(size_t)i * 128 + l * 2]);
    float o0 = a20 * xv.x, o1 = a20 * xv.y;
    #pragma unroll
    for (int k = 0; k < 16; ++k) {
        int nk = __shfl(nlv, k, 64);
        float2 vv = *reinterpret_cast<const float2*>(&xVV[(size_t)nk * 128 + l * 2]);
        o0 += w[k] * vv.x;
        o1 += w[k] * vv.y;
    }
    float sq = o0 * o0 + o1 * o1;
    #pragma unroll
    for (int off = 32; off >= 1; off >>= 1)
        sq += __shfl_xor(sq, off, 64);
    float d = fmaxf(sqrtf(sq), 1e-12f);
    float rd = 1.f / d;
    float2 o = {o0 * rd, o1 * rd};
    *reinterpret_cast<float2*>(&outp[(size_t)i * 128 + l * 2]) = o;
}

extern "C" void kernel_launch(void* const* d_in, const int* in_sizes, int n_in,
                              void* d_out, int out_size, void* d_ws, size_t ws_size,
                              hipStream_t stream) {
    const float* x     = (const float*)d_in[0];
    const int*   nlist = (const int*)d_in[1];
    const float* Q     = (const float*)d_in[2];
    const float* K     = (const float*)d_in[3];
    const float* V     = (const float*)d_in[4];
    float* out = (float*)d_out;
    int n = in_sizes[0] / 128;   // 50000

    float* ws   = (float*)d_ws;
    float* QKt  = ws;                  // 16384
    float* MT   = ws + 16384;          // 16384
    float* VV   = ws + 32768;          // 16384
    float* xQK  = ws + 49152;
    size_t stride = (size_t)n * 128;
    float* uarr = xQK + stride;
    float* xV   = uarr + stride;
    float* xVV  = xV + stride;

    small_mm_a<<<dim3(16, 2), 256, 0, stream>>>(Q, K, V, QKt, VV);
    small_mm_b<<<dim3(16), 256, 0, stream>>>(QKt, V, MT);
    dim3 g2((n + 127) / 128, 4);
    proj_gemm<<<g2, 256, 0, stream>>>(x, QKt, MT, V, VV, xQK, uarr, xV, xVV, n);
    node_attn<<<(n + 3) / 4, 256, 0, stream>>>(nlist, x, xQK, uarr, xV, xVV, out, n);
}